// Round 8
// baseline (54.770 us; speedup 1.0000x reference)
//
#include <hip/hip_runtime.h>

// Problem constants (from reference): B=8, N=4096, D=3
#define B_ 8
#define N_ 4096
#define P_ 8                            // own points per lane
#define OWN_PER_BLOCK (64 * P_)         // 512
#define OWN_CHUNKS (N_ / OWN_PER_BLOCK) // 8
#define OPP_CHUNKS 16                   // opposite range split across blocks
#define OPP_PER_BLOCK (N_ / OPP_CHUNKS) // 256
#define OPP_PER_WAVE (OPP_PER_BLOCK / 4) // 64
#define RED_BLOCKS ((2 * B_ * N_) / 256) // 256

typedef __attribute__((ext_vector_type(16))) float fv16;

// Prep: tab[src][b][n] = (-2qx, -2qy, -2qz, |q|^2); src 0 = x, 1 = y.
// Also zero-inits the f64 accumulators and the reduce completion counter.
__global__ __launch_bounds__(256) void chamfer_prep(
        const float* __restrict__ x, const float* __restrict__ y,
        float4* __restrict__ tab, double* __restrict__ acc,
        unsigned* __restrict__ cnt) {
    const int id  = blockIdx.x * 256 + threadIdx.x;  // 0..65535
    const int src = id >> 15;
    const int rem = id & 32767;                      // b*N + n
    const float* s_ = src ? y : x;
    const float a = s_[3 * rem], b = s_[3 * rem + 1], c = s_[3 * rem + 2];
    tab[id] = make_float4(-2.f * a, -2.f * b, -2.f * c, a * a + b * b + c * c);
    if (blockIdx.x == 0) {
        if (threadIdx.x < 2) acc[threadIdx.x] = 0.0;
        if (threadIdx.x == 2) *cnt = 0u;
    }
}

// Issue 2 scalar 64B loads (8 points). "=&s" early-clobber: outputs cannot
// overlap the address pair.
#define ISSUE2(B0, B1, AD) \
    asm volatile("s_load_dwordx16 %0, %2, 0x0\n\t" \
                 "s_load_dwordx16 %1, %2, 0x40" \
                 : "=&s"(B0), "=&s"(B1) : "s"(AD))

// Wait for all outstanding scalar loads (completes A0/A1), then issue the
// next chunk into B0/B1. A0/A1 tied "+s" so consumers stay below the wait.
// (Counted lgkmcnt is unsafe for SMEM — s_load may return out of order —
// so the pipeline is exactly 2-deep with lgkmcnt(0) waits.)
#define WAIT_ISSUE2(B0, B1, A0, A1, AD) \
    asm volatile("s_waitcnt lgkmcnt(0)\n\t" \
                 "s_load_dwordx16 %0, %4, 0x0\n\t" \
                 "s_load_dwordx16 %1, %4, 0x40" \
                 : "=&s"(B0), "=&s"(B1), "+s"(A0), "+s"(A1) : "s"(AD))

// Drain only — no new issues.
#define WAIT_ONLY(A0, A1) \
    asm volatile("s_waitcnt lgkmcnt(0)" : "+s"(A0), "+s"(A1))

// Dot-form eval of point J: e = |q|^2 - 2 q.p  (true d^2 = e + |p|^2, added
// once in the epilogue). Per opp point: 24 FMA + 8 min + 1 shared s->v mov.
#define EVAL_PT(AV, J) do { \
    const float nx = (AV)[4 * (J) + 0]; \
    const float ny = (AV)[4 * (J) + 1]; \
    const float nz = (AV)[4 * (J) + 2]; \
    const float w  = (AV)[4 * (J) + 3]; \
    float e0 = fmaf(nz, pz0, w); e0 = fmaf(ny, py0, e0); e0 = fmaf(nx, px0, e0); \
    float e1 = fmaf(nz, pz1, w); e1 = fmaf(ny, py1, e1); e1 = fmaf(nx, px1, e1); \
    float e2 = fmaf(nz, pz2, w); e2 = fmaf(ny, py2, e2); e2 = fmaf(nx, px2, e2); \
    float e3 = fmaf(nz, pz3, w); e3 = fmaf(ny, py3, e3); e3 = fmaf(nx, px3, e3); \
    float e4 = fmaf(nz, pz4, w); e4 = fmaf(ny, py4, e4); e4 = fmaf(nx, px4, e4); \
    float e5 = fmaf(nz, pz5, w); e5 = fmaf(ny, py5, e5); e5 = fmaf(nx, px5, e5); \
    float e6 = fmaf(nz, pz6, w); e6 = fmaf(ny, py6, e6); e6 = fmaf(nx, px6, e6); \
    float e7 = fmaf(nz, pz7, w); e7 = fmaf(ny, py7, e7); e7 = fmaf(nx, px7, e7); \
    if ((J) & 1) { m0o = fminf(m0o, e0); m1o = fminf(m1o, e1); \
                   m2o = fminf(m2o, e2); m3o = fminf(m3o, e3); \
                   m4o = fminf(m4o, e4); m5o = fminf(m5o, e5); \
                   m6o = fminf(m6o, e6); m7o = fminf(m7o, e7); } \
    else         { m0e = fminf(m0e, e0); m1e = fminf(m1e, e1); \
                   m2e = fminf(m2e, e2); m3e = fminf(m3e, e3); \
                   m4e = fminf(m4e, e4); m5e = fminf(m5e, e5); \
                   m6e = fminf(m6e, e6); m7e = fminf(m7e, e7); } \
} while (0)

#define COMP8(A0, A1) do { \
    EVAL_PT(A0, 0); EVAL_PT(A0, 1); EVAL_PT(A0, 2); EVAL_PT(A0, 3); \
    EVAL_PT(A1, 0); EVAL_PT(A1, 1); EVAL_PT(A1, 2); EVAL_PT(A1, 3); \
} while (0)

// dir 0: own = y (j), opp = x (tab slice 0) -> acc[0]  (min over axis 1)
// dir 1: own = x (i), opp = y (tab slice 1) -> acc[1]  (min over axis 2)
// Grid (OWN_CHUNKS, B_*OPP_CHUNKS, 2) = 8*128*2 = 2048 blocks = 8 blocks/CU.
// Each lane owns 8 points; wave scans a 64-point opp slice from SGPRs.
__global__ __launch_bounds__(256) void chamfer_min_kernel(
        const float* __restrict__ x, const float* __restrict__ y,
        const float4* __restrict__ tab, float* __restrict__ part) {
    const int dir  = blockIdx.z;
    const int b    = blockIdx.y >> 4;
    const int oc   = blockIdx.y & 15;
    const int base = blockIdx.x * OWN_PER_BLOCK;

    const float* own = dir ? x : y;

    const int t = threadIdx.x;
    const int l = t & 63;
    const int su = __builtin_amdgcn_readfirstlane(t >> 6);  // wave id, SGPR

    // Per-lane own points (coalesced 12 B/lane per group of 64).
    const float* op0 = own + ((size_t)b * N_ + base + l) * 3;
    const float px0 = op0[0],    py0 = op0[1],    pz0 = op0[2];
    const float px1 = op0[192],  py1 = op0[193],  pz1 = op0[194];
    const float px2 = op0[384],  py2 = op0[385],  pz2 = op0[386];
    const float px3 = op0[576],  py3 = op0[577],  pz3 = op0[578];
    const float px4 = op0[768],  py4 = op0[769],  pz4 = op0[770];
    const float px5 = op0[960],  py5 = op0[961],  pz5 = op0[962];
    const float px6 = op0[1152], py6 = op0[1153], pz6 = op0[1154];
    const float px7 = op0[1344], py7 = op0[1345], pz7 = op0[1346];

    float m0e = 1e30f, m0o = 1e30f, m1e = 1e30f, m1o = 1e30f;
    float m2e = 1e30f, m2o = 1e30f, m3e = 1e30f, m3o = 1e30f;
    float m4e = 1e30f, m4o = 1e30f, m5e = 1e30f, m5o = 1e30f;
    float m6e = 1e30f, m6o = 1e30f, m7e = 1e30f, m7o = 1e30f;

    // Uniform SGPR address of this wave's 64-point table slice.
    const float4* tslice = tab + (((size_t)dir * B_ + b) * N_
                                  + oc * OPP_PER_BLOCK + su * OPP_PER_WAVE);
    unsigned long long ad = (unsigned long long)tslice;

    // 8 chunks of 8 points. Pipeline: 1 + 3*2 + 1 issues = 8 exactly;
    // every issue is waited; no overread past the slice.
    fv16 a0, a1, b0, b1;
    ISSUE2(a0, a1, ad); ad += 128;
#pragma unroll 1
    for (int it = 0; it < 3; ++it) {
        WAIT_ISSUE2(b0, b1, a0, a1, ad); ad += 128;
        COMP8(a0, a1);
        WAIT_ISSUE2(a0, a1, b0, b1, ad); ad += 128;
        COMP8(b0, b1);
    }
    WAIT_ISSUE2(b0, b1, a0, a1, ad);    // wait chunk 6, issue chunk 7
    COMP8(a0, a1);                      // chunk 6
    WAIT_ONLY(b0, b1);                  // drain chunk 7
    COMP8(b0, b1);                      // chunk 7

    // d^2 = min_e + |p|^2; cross-wave min; coalesced partial writes.
    __shared__ float red[4][OWN_PER_BLOCK];
    red[su][l]       = fminf(m0e, m0o) + (px0 * px0 + py0 * py0 + pz0 * pz0);
    red[su][64 + l]  = fminf(m1e, m1o) + (px1 * px1 + py1 * py1 + pz1 * pz1);
    red[su][128 + l] = fminf(m2e, m2o) + (px2 * px2 + py2 * py2 + pz2 * pz2);
    red[su][192 + l] = fminf(m3e, m3o) + (px3 * px3 + py3 * py3 + pz3 * pz3);
    red[su][256 + l] = fminf(m4e, m4o) + (px4 * px4 + py4 * py4 + pz4 * pz4);
    red[su][320 + l] = fminf(m5e, m5o) + (px5 * px5 + py5 * py5 + pz5 * pz5);
    red[su][384 + l] = fminf(m6e, m6o) + (px6 * px6 + py6 * py6 + pz6 * pz6);
    red[su][448 + l] = fminf(m7e, m7o) + (px7 * px7 + py7 * py7 + pz7 * pz7);
    __syncthreads();

    float* pr = part + (((size_t)dir * B_ + b) * OPP_CHUNKS + oc) * N_ + base;
#pragma unroll
    for (int k = 0; k < 2; ++k) {
        const int i = k * 256 + t;
        pr[i] = fminf(fminf(red[0][i], red[1][i]), fminf(red[2][i], red[3][i]));
    }
}

// Combine OPP_CHUNKS partials, apply mask, accumulate in f64; the last block
// to finish also writes the final scalar (fused finalize).
__global__ __launch_bounds__(256) void chamfer_reduce_kernel(
        const float* __restrict__ part,
        const float* __restrict__ xm, const float* __restrict__ ym,
        double* __restrict__ acc, unsigned* __restrict__ cnt,
        float* __restrict__ out) {
    const int id  = blockIdx.x * 256 + threadIdx.x;
    const int dir = id >> 15;            // uniform per wave
    const int rem = id & 32767;
    const int b   = rem >> 12;
    const int n   = rem & (N_ - 1);

    const float* msk = dir ? ym : xm;

    float mn = 1e30f;
#pragma unroll
    for (int oc = 0; oc < OPP_CHUNKS; ++oc)
        mn = fminf(mn, part[(((size_t)dir * B_ + b) * OPP_CHUNKS + oc) * N_ + n]);

    double val = (double)(msk[(size_t)b * N_ + n] * mn);
    for (int off = 32; off; off >>= 1)
        val += __shfl_down(val, off);
    if ((threadIdx.x & 63) == 0)
        atomicAdd(&acc[dir], val);

    __syncthreads();
    if (threadIdx.x == 0) {
        __threadfence();
        unsigned old = atomicAdd(cnt, 1u);
        if (old == RED_BLOCKS - 1) {
            __threadfence();
            double d = (acc[0] - acc[1]) / (double)(B_ * N_);
            out[0] = (float)(d * d);
        }
    }
}

extern "C" void kernel_launch(void* const* d_in, const int* in_sizes, int n_in,
                              void* d_out, int out_size, void* d_ws, size_t ws_size,
                              hipStream_t stream) {
    const float* x  = (const float*)d_in[0];
    const float* y  = (const float*)d_in[1];
    const float* xm = (const float*)d_in[2];
    const float* ym = (const float*)d_in[3];
    float* out = (float*)d_out;

    double*   acc = (double*)d_ws;                          // 16 B
    unsigned* cnt = (unsigned*)((char*)d_ws + 16);          // 4 B
    float4*   tab = (float4*)((char*)d_ws + 256);           // 1 MB
    float*    prt = (float*)((char*)d_ws + 256 + (size_t)2 * B_ * N_ * 16); // 4 MB

    chamfer_prep<<<RED_BLOCKS, 256, 0, stream>>>(x, y, tab, acc, cnt);

    dim3 grid(OWN_CHUNKS, B_ * OPP_CHUNKS, 2);              // 2048 blocks
    chamfer_min_kernel<<<grid, 256, 0, stream>>>(x, y, tab, prt);

    chamfer_reduce_kernel<<<RED_BLOCKS, 256, 0, stream>>>(prt, xm, ym, acc, cnt, out);
}

// Round 9
// 43.931 us; speedup vs baseline: 1.2467x; 1.2467x over previous
//
#include <hip/hip_runtime.h>

// Problem constants (from reference): B=8, N=4096, D=3
#define B_ 8
#define N_ 4096
#define P_ 8                            // own points per lane
#define OWN_PER_BLOCK (64 * P_)         // 512
#define OWN_CHUNKS (N_ / OWN_PER_BLOCK) // 8
#define OPP_CHUNKS 16                   // opposite range split across blocks
#define OPP_SLICE (N_ / OPP_CHUNKS)     // 256 opp points per block
#define OPP_PER_WAVE (OPP_SLICE / 4)    // 64
#define RED_BLOCKS ((2 * B_ * N_) / 256) // 256

// Dot-form eval of one opp point q = (-2qx,-2qy,-2qz,|q|^2), all VGPR
// operands (no SGPR-port constraint): e = |q|^2 - 2 q.p, 3 FMA + 1 min per
// own point = 32 VALU per opp point.
#define EVAL_Q(Q) do { \
    float e0 = fmaf((Q).z, pz0, (Q).w); e0 = fmaf((Q).y, py0, e0); e0 = fmaf((Q).x, px0, e0); m0 = fminf(m0, e0); \
    float e1 = fmaf((Q).z, pz1, (Q).w); e1 = fmaf((Q).y, py1, e1); e1 = fmaf((Q).x, px1, e1); m1 = fminf(m1, e1); \
    float e2 = fmaf((Q).z, pz2, (Q).w); e2 = fmaf((Q).y, py2, e2); e2 = fmaf((Q).x, px2, e2); m2 = fminf(m2, e2); \
    float e3 = fmaf((Q).z, pz3, (Q).w); e3 = fmaf((Q).y, py3, e3); e3 = fmaf((Q).x, px3, e3); m3 = fminf(m3, e3); \
    float e4 = fmaf((Q).z, pz4, (Q).w); e4 = fmaf((Q).y, py4, e4); e4 = fmaf((Q).x, px4, e4); m4 = fminf(m4, e4); \
    float e5 = fmaf((Q).z, pz5, (Q).w); e5 = fmaf((Q).y, py5, e5); e5 = fmaf((Q).x, px5, e5); m5 = fminf(m5, e5); \
    float e6 = fmaf((Q).z, pz6, (Q).w); e6 = fmaf((Q).y, py6, e6); e6 = fmaf((Q).x, px6, e6); m6 = fminf(m6, e6); \
    float e7 = fmaf((Q).z, pz7, (Q).w); e7 = fmaf((Q).y, py7, e7); e7 = fmaf((Q).x, px7, e7); m7 = fminf(m7, e7); \
} while (0)

// dir 0: own = y (j), opp = x -> acc[0]  (min over axis 1)
// dir 1: own = x (i), opp = y -> acc[1]  (min over axis 2)
// Grid (OWN_CHUNKS, B_*OPP_CHUNKS, 2) = 8*128*2 = 2048 blocks = 8 blocks/CU.
// Fused: stages its 256-pt opp slice into LDS in dot form, then hot loop is
// broadcast ds_read_b128 + FMA/min. No SMEM, no prep kernel.
__global__ __launch_bounds__(256, 8) void chamfer_min_kernel(
        const float* __restrict__ x, const float* __restrict__ y,
        float* __restrict__ part, double* __restrict__ acc,
        unsigned* __restrict__ cnt) {
    const int dir  = blockIdx.z;
    const int b    = blockIdx.y >> 4;
    const int oc   = blockIdx.y & 15;
    const int base = blockIdx.x * OWN_PER_BLOCK;

    const float* own = dir ? x : y;
    const float* opp = dir ? y : x;

    const int t = threadIdx.x;
    const int l = t & 63;
    const int su = __builtin_amdgcn_readfirstlane(t >> 6);  // wave id

    // Zero the f64 accumulators + completion counter (one block; no other
    // block touches them until the reduce kernel, which runs after).
    if (blockIdx.x == 0 && blockIdx.y == 0 && blockIdx.z == 0) {
        if (t < 2) acc[t] = 0.0;
        if (t == 2) *cnt = 0u;
    }

    // Stage opp slice into LDS in dot form: (-2qx, -2qy, -2qz, |q|^2).
    __shared__ float4 sq[OPP_SLICE];       // 4 KB
    {
        const float* ob = opp + ((size_t)b * N_ + oc * OPP_SLICE) * 3;
        const float a = ob[3 * t], bb = ob[3 * t + 1], c = ob[3 * t + 2];
        sq[t] = make_float4(-2.f * a, -2.f * bb, -2.f * c,
                            a * a + bb * bb + c * c);
    }

    // Per-lane own points (coalesced 12 B/lane per group of 64).
    const float* op0 = own + ((size_t)b * N_ + base + l) * 3;
    const float px0 = op0[0],    py0 = op0[1],    pz0 = op0[2];
    const float px1 = op0[192],  py1 = op0[193],  pz1 = op0[194];
    const float px2 = op0[384],  py2 = op0[385],  pz2 = op0[386];
    const float px3 = op0[576],  py3 = op0[577],  pz3 = op0[578];
    const float px4 = op0[768],  py4 = op0[769],  pz4 = op0[770];
    const float px5 = op0[960],  py5 = op0[961],  pz5 = op0[962];
    const float px6 = op0[1152], py6 = op0[1153], pz6 = op0[1154];
    const float px7 = op0[1344], py7 = op0[1345], pz7 = op0[1346];

    __syncthreads();

    float m0 = 1e30f, m1 = 1e30f, m2 = 1e30f, m3 = 1e30f;
    float m4 = 1e30f, m5 = 1e30f, m6 = 1e30f, m7 = 1e30f;

    // Hot loop: wave su scans its 64-pt quarter via broadcast ds_read_b128.
    // 32 VALU per ds_read -> LDS pipe (12 cyc/b128/CU) stays under VALU.
    const float4* qs = &sq[su * OPP_PER_WAVE];
#pragma unroll 4
    for (int k = 0; k < OPP_PER_WAVE; ++k) {
        const float4 q = qs[k];
        EVAL_Q(q);
    }

    // d^2 = min_e + |p|^2; cross-wave min; coalesced partial writes.
    __shared__ float red[4][OWN_PER_BLOCK]; // 8 KB
    red[su][l]       = m0 + (px0 * px0 + py0 * py0 + pz0 * pz0);
    red[su][64 + l]  = m1 + (px1 * px1 + py1 * py1 + pz1 * pz1);
    red[su][128 + l] = m2 + (px2 * px2 + py2 * py2 + pz2 * pz2);
    red[su][192 + l] = m3 + (px3 * px3 + py3 * py3 + pz3 * pz3);
    red[su][256 + l] = m4 + (px4 * px4 + py4 * py4 + pz4 * pz4);
    red[su][320 + l] = m5 + (px5 * px5 + py5 * py5 + pz5 * pz5);
    red[su][384 + l] = m6 + (px6 * px6 + py6 * py6 + pz6 * pz6);
    red[su][448 + l] = m7 + (px7 * px7 + py7 * py7 + pz7 * pz7);
    __syncthreads();

    float* pr = part + (((size_t)dir * B_ + b) * OPP_CHUNKS + oc) * N_ + base;
#pragma unroll
    for (int k = 0; k < 2; ++k) {
        const int i = k * 256 + t;
        pr[i] = fminf(fminf(red[0][i], red[1][i]), fminf(red[2][i], red[3][i]));
    }
}

// Combine OPP_CHUNKS partials, apply mask, accumulate in f64; the last block
// to finish writes the final scalar (fused finalize).
__global__ __launch_bounds__(256) void chamfer_reduce_kernel(
        const float* __restrict__ part,
        const float* __restrict__ xm, const float* __restrict__ ym,
        double* __restrict__ acc, unsigned* __restrict__ cnt,
        float* __restrict__ out) {
    const int id  = blockIdx.x * 256 + threadIdx.x;
    const int dir = id >> 15;            // uniform per wave
    const int rem = id & 32767;
    const int b   = rem >> 12;
    const int n   = rem & (N_ - 1);

    const float* msk = dir ? ym : xm;

    float mn = 1e30f;
#pragma unroll
    for (int oc = 0; oc < OPP_CHUNKS; ++oc)
        mn = fminf(mn, part[(((size_t)dir * B_ + b) * OPP_CHUNKS + oc) * N_ + n]);

    double val = (double)(msk[(size_t)b * N_ + n] * mn);
    for (int off = 32; off; off >>= 1)
        val += __shfl_down(val, off);
    if ((threadIdx.x & 63) == 0)
        atomicAdd(&acc[dir], val);

    __syncthreads();
    if (threadIdx.x == 0) {
        __threadfence();
        unsigned old = atomicAdd(cnt, 1u);
        if (old == RED_BLOCKS - 1) {
            __threadfence();
            double d = (acc[0] - acc[1]) / (double)(B_ * N_);
            out[0] = (float)(d * d);
        }
    }
}

extern "C" void kernel_launch(void* const* d_in, const int* in_sizes, int n_in,
                              void* d_out, int out_size, void* d_ws, size_t ws_size,
                              hipStream_t stream) {
    const float* x  = (const float*)d_in[0];
    const float* y  = (const float*)d_in[1];
    const float* xm = (const float*)d_in[2];
    const float* ym = (const float*)d_in[3];
    float* out = (float*)d_out;

    double*   acc = (double*)d_ws;                          // 16 B
    unsigned* cnt = (unsigned*)((char*)d_ws + 16);          // 4 B
    float*    prt = (float*)((char*)d_ws + 256);            // 2*8*16*4096*4 = 4 MB

    dim3 grid(OWN_CHUNKS, B_ * OPP_CHUNKS, 2);              // 2048 blocks
    chamfer_min_kernel<<<grid, 256, 0, stream>>>(x, y, prt, acc, cnt);

    chamfer_reduce_kernel<<<RED_BLOCKS, 256, 0, stream>>>(prt, xm, ym, acc, cnt, out);
}